// Round 2
// baseline (1485.025 us; speedup 1.0000x reference)
//
#include <hip/hip_runtime.h>
#include <math.h>

#define N_NODES 50000
#define N_EDGES 800000
#define N_TOT   850000   // edges + self loops

// ----------------------------- utility kernels -----------------------------
__global__ void zero_int_kernel(int* p, int n) {
    int i = blockIdx.x * blockDim.x + threadIdx.x;
    if (i < n) p[i] = 0;
}

__global__ void copy_int_kernel(const int* a, int* b, int n) {
    int i = blockIdx.x * blockDim.x + threadIdx.x;
    if (i < n) b[i] = a[i];
}

// ----------------------------- CSR build -----------------------------------
// NOTE: harness delivers integer inputs as int32 (int64 in reference is cast).
__global__ void deg_hist_kernel(const int* __restrict__ ei, int* __restrict__ deg) {
    int e = blockIdx.x * blockDim.x + threadIdx.x;
    if (e >= N_TOT) return;
    int dst = (e < N_EDGES) ? ei[N_EDGES + e] : (e - N_EDGES);
    atomicAdd(&deg[dst], 1);
}

// single block, 256 threads: exclusive scan of deg[0..N_NODES) -> off[0..N_NODES]
__global__ void scan_offsets_kernel(const int* __restrict__ deg, int* __restrict__ off) {
    __shared__ int sa[256], sb[256];
    const int n = N_NODES;
    int t = threadIdx.x;
    const int chunk = (n + 255) / 256;
    int base = t * chunk;
    int s = 0;
    for (int i = 0; i < chunk; i++) {
        int idx = base + i;
        if (idx < n) s += deg[idx];
    }
    sa[t] = s;
    __syncthreads();
    int* src_ = sa; int* dst_ = sb;
    for (int d = 1; d < 256; d <<= 1) {
        dst_[t] = (t >= d) ? (src_[t - d] + src_[t]) : src_[t];
        __syncthreads();
        int* tmp = src_; src_ = dst_; dst_ = tmp;
    }
    int inc  = src_[t];
    int excl = inc - s;
    int run = excl;
    for (int i = 0; i < chunk; i++) {
        int idx = base + i;
        if (idx < n) { off[idx] = run; run += deg[idx]; }
    }
    if (t == 255) off[n] = src_[255];
}

__global__ void fill_csr_kernel(const int* __restrict__ ei, int* __restrict__ cursor,
                                int* __restrict__ csr_src) {
    int e = blockIdx.x * blockDim.x + threadIdx.x;
    if (e >= N_TOT) return;
    int src, dst;
    if (e < N_EDGES) { src = ei[e]; dst = ei[N_EDGES + e]; }
    else             { src = dst = e - N_EDGES; }
    int pos = atomicAdd(&cursor[dst], 1);
    csr_src[pos] = src;
}

// ----------------------------- GEMM: h = x @ W ------------------------------
// block = 256 threads, 32 nodes per block. W is [Cin, Cout] row-major.
template<int Cin, int Cout>
__global__ void gemm_tile_kernel(const float* __restrict__ x, const float* __restrict__ W,
                                 float* __restrict__ h) {
    static_assert(256 % Cout == 0 || Cout % 256 == 0, "");
    __shared__ float xs[32][Cin];
    int n0 = blockIdx.x * 32;
    int tid = threadIdx.x;
    for (int i = tid; i < 32 * Cin; i += 256) {
        int n = i / Cin, k = i % Cin;
        int gn = n0 + n;
        xs[n][k] = (gn < N_NODES) ? x[(size_t)gn * Cin + k] : 0.f;
    }
    __syncthreads();
    constexpr int NS   = 256 / Cout;   // distinct node-subgroups per block
    constexpr int NACC = 32 / NS;      // nodes per thread
    int oc   = tid % Cout;
    int nsub = tid / Cout;
    float acc[NACC];
#pragma unroll
    for (int i = 0; i < NACC; i++) acc[i] = 0.f;
    for (int k = 0; k < Cin; k++) {
        float w = W[(size_t)k * Cout + oc];
#pragma unroll
        for (int i = 0; i < NACC; i++) acc[i] += xs[nsub + i * NS][k] * w;
    }
#pragma unroll
    for (int i = 0; i < NACC; i++) {
        int gn = n0 + nsub + i * NS;
        if (gn < N_NODES) h[(size_t)gn * Cout + oc] = acc[i];
    }
}

// ------------------- per-node attention logits al_s, al_d -------------------
template<int H, int C>
__global__ void attn_logits_kernel(const float* __restrict__ h, const float* __restrict__ a_src,
                                   const float* __restrict__ a_dst, float* __restrict__ al_s,
                                   float* __restrict__ al_d) {
    int i = blockIdx.x * blockDim.x + threadIdx.x;   // (n, head)
    if (i >= N_NODES * H) return;
    int n = i / H, head = i % H;
    const float* hp = h + (size_t)n * H * C + head * C;
    float ss = 0.f, sd = 0.f;
    for (int c = 0; c < C; c++) {
        float v = hp[c];
        ss += v * a_src[head * C + c];
        sd += v * a_dst[head * C + c];
    }
    al_s[i] = ss;
    al_d[i] = sd;
}

// ------------------------- GAT softmax + aggregation ------------------------
// block = NPB * H * C = 256 threads. One group of H*C threads per node.
// Softmax stats reduced with shfl within GR-lane groups (no __syncthreads).
template<int H, int C, int NPB, bool RELU>
__global__ void gat_agg_kernel(const float* __restrict__ h, const float* __restrict__ al_s,
                               const float* __restrict__ al_d, const int* __restrict__ off,
                               const int* __restrict__ csr_src, const float* __restrict__ bias,
                               float* __restrict__ out) {
    constexpr int HC = H * C;
    constexpr int GR = (C < 64) ? C : 64;   // reduction group width (within one wave)
    int tid = threadIdx.x;
    int node_local = tid / HC;
    int rem = tid % HC;
    int head = rem / C;
    int node = blockIdx.x * NPB + node_local;
    if (node >= N_NODES) return;

    int r0 = off[node], r1 = off[node + 1];
    float ald = al_d[node * H + head];
    int lane = tid % GR;

    // ---- phase 1: online softmax (m, s) over incoming edges ----
    float m = -INFINITY, s = 0.f;
    for (int j = r0 + lane; j < r1; j += GR) {
        int src = csr_src[j];
        float e = al_s[src * H + head] + ald;
        e = (e > 0.f) ? e : 0.2f * e;
        float M = fmaxf(m, e);
        s = s * __expf(m - M) + __expf(e - M);
        m = M;
    }
#pragma unroll
    for (int k = 1; k < GR; k <<= 1) {
        float om = __shfl_xor(m, k, 64);
        float os = __shfl_xor(s, k, 64);
        float M = fmaxf(m, om);
        float S;
        if (M == -INFINITY) S = 0.f;
        else S = s * __expf(m - M) + os * __expf(om - M);
        m = M; s = S;
    }
    float inv_s = 1.f / s;   // s > 0: every node has a self loop

    // ---- phase 2: weighted aggregation, one output channel per thread ----
    float acc = 0.f;
    for (int j = r0; j < r1; j++) {
        int src = csr_src[j];
        float e = al_s[src * H + head] + ald;
        e = (e > 0.f) ? e : 0.2f * e;
        float w = __expf(e - m) * inv_s;
        acc += w * h[(size_t)src * HC + rem];
    }
    acc += bias[rem];
    if (RELU) acc = fmaxf(acc, 0.f);
    out[(size_t)node * HC + rem] = acc;
}

// ------------------------------- launcher -----------------------------------
extern "C" void kernel_launch(void* const* d_in, const int* in_sizes, int n_in,
                              void* d_out, int out_size, void* d_ws, size_t ws_size,
                              hipStream_t stream) {
    const float* x   = (const float*)d_in[0];
    const int*   ei  = (const int*)d_in[1];   // harness casts int64 -> int32
    const float* W1  = (const float*)d_in[2];
    const float* as1 = (const float*)d_in[3];
    const float* ad1 = (const float*)d_in[4];
    const float* b1  = (const float*)d_in[5];
    const float* W2  = (const float*)d_in[6];
    const float* as2 = (const float*)d_in[7];
    const float* ad2 = (const float*)d_in[8];
    const float* b2  = (const float*)d_in[9];
    const float* W3  = (const float*)d_in[10];
    const float* as3 = (const float*)d_in[11];
    const float* ad3 = (const float*)d_in[12];
    const float* b3  = (const float*)d_in[13];
    const float* W4  = (const float*)d_in[14];
    const float* as4 = (const float*)d_in[15];
    const float* ad4 = (const float*)d_in[16];
    const float* b4  = (const float*)d_in[17];

    char* ws = (char*)d_ws;
    size_t o = 0;
    auto alloc = [&](size_t bytes) -> void* {
        void* p = ws + o;
        o = (o + bytes + 255) & ~(size_t)255;
        return p;
    };
    float* feat_a  = (float*)alloc((size_t)N_NODES * 256 * 4);  // 51.2 MB
    float* feat_b  = (float*)alloc((size_t)N_NODES * 32 * 4);   // 6.4 MB
    float* h_buf   = (float*)alloc((size_t)N_NODES * 256 * 4);  // 51.2 MB
    float* al_s    = (float*)alloc((size_t)N_NODES * 8 * 4);
    float* al_d    = (float*)alloc((size_t)N_NODES * 8 * 4);
    int*   deg     = (int*)alloc((size_t)(N_NODES + 1) * 4);
    int*   off     = (int*)alloc((size_t)(N_NODES + 1) * 4);
    int*   cursor  = (int*)alloc((size_t)N_NODES * 4);
    int*   csr_src = (int*)alloc((size_t)N_TOT * 4);

    const int TPB = 256;
    int nb_nodes = (N_NODES + TPB - 1) / TPB;
    int nb_edges = (N_TOT + TPB - 1) / TPB;
    int nb_gemm  = (N_NODES + 31) / 32;

    // ---- CSR build (by dst) ----
    zero_int_kernel<<<nb_nodes, TPB, 0, stream>>>(deg, N_NODES);
    deg_hist_kernel<<<nb_edges, TPB, 0, stream>>>(ei, deg);
    scan_offsets_kernel<<<1, TPB, 0, stream>>>(deg, off);
    copy_int_kernel<<<nb_nodes, TPB, 0, stream>>>(off, cursor, N_NODES);
    fill_csr_kernel<<<nb_edges, TPB, 0, stream>>>(ei, cursor, csr_src);

    // ---- Layer 1: 128 -> (8 heads x 32), ReLU ----
    gemm_tile_kernel<128, 256><<<nb_gemm, TPB, 0, stream>>>(x, W1, h_buf);
    attn_logits_kernel<8, 32><<<(N_NODES * 8 + TPB - 1) / TPB, TPB, 0, stream>>>(h_buf, as1, ad1, al_s, al_d);
    gat_agg_kernel<8, 32, 1, true><<<N_NODES, TPB, 0, stream>>>(h_buf, al_s, al_d, off, csr_src, b1, feat_a);

    // ---- Layer 2: 256 -> 32, 1 head ----
    gemm_tile_kernel<256, 32><<<nb_gemm, TPB, 0, stream>>>(feat_a, W2, h_buf);
    attn_logits_kernel<1, 32><<<(N_NODES + TPB - 1) / TPB, TPB, 0, stream>>>(h_buf, as2, ad2, al_s, al_d);
    gat_agg_kernel<1, 32, 8, false><<<N_NODES / 8, TPB, 0, stream>>>(h_buf, al_s, al_d, off, csr_src, b2, feat_b);

    // ---- Layer 3: 32 -> (8 heads x 32), ReLU ----
    gemm_tile_kernel<32, 256><<<nb_gemm, TPB, 0, stream>>>(feat_b, W3, h_buf);
    attn_logits_kernel<8, 32><<<(N_NODES * 8 + TPB - 1) / TPB, TPB, 0, stream>>>(h_buf, as3, ad3, al_s, al_d);
    gat_agg_kernel<8, 32, 1, true><<<N_NODES, TPB, 0, stream>>>(h_buf, al_s, al_d, off, csr_src, b3, feat_a);

    // ---- Layer 4: 256 -> 128, 1 head ----
    gemm_tile_kernel<256, 128><<<nb_gemm, TPB, 0, stream>>>(feat_a, W4, h_buf);
    attn_logits_kernel<1, 128><<<(N_NODES + TPB - 1) / TPB, TPB, 0, stream>>>(h_buf, as4, ad4, al_s, al_d);
    gat_agg_kernel<1, 128, 2, false><<<N_NODES / 2, TPB, 0, stream>>>(h_buf, al_s, al_d, off, csr_src, b4, (float*)d_out);
}

// Round 3
// 1023.904 us; speedup vs baseline: 1.4504x; 1.4504x over previous
//
#include <hip/hip_runtime.h>
#include <math.h>

#define N_NODES 50000
#define N_EDGES 800000
#define N_TOT   850000   // edges + self loops

// ----------------------------- utility kernels -----------------------------
__global__ void zero_int_kernel(int* p, int n) {
    int i = blockIdx.x * blockDim.x + threadIdx.x;
    if (i < n) p[i] = 0;
}

__global__ void copy_int_kernel(const int* a, int* b, int n) {
    int i = blockIdx.x * blockDim.x + threadIdx.x;
    if (i < n) b[i] = a[i];
}

// ----------------------------- CSR build -----------------------------------
// NOTE: harness delivers integer inputs as int32 (int64 in reference is cast).
__global__ void deg_hist_kernel(const int* __restrict__ ei, int* __restrict__ deg) {
    int e = blockIdx.x * blockDim.x + threadIdx.x;
    if (e >= N_TOT) return;
    int dst = (e < N_EDGES) ? ei[N_EDGES + e] : (e - N_EDGES);
    atomicAdd(&deg[dst], 1);
}

// single block, 256 threads: exclusive scan of deg[0..N_NODES) -> off[0..N_NODES]
__global__ void scan_offsets_kernel(const int* __restrict__ deg, int* __restrict__ off) {
    __shared__ int sa[256], sb[256];
    const int n = N_NODES;
    int t = threadIdx.x;
    const int chunk = (n + 255) / 256;
    int base = t * chunk;
    int s = 0;
    for (int i = 0; i < chunk; i++) {
        int idx = base + i;
        if (idx < n) s += deg[idx];
    }
    sa[t] = s;
    __syncthreads();
    int* src_ = sa; int* dst_ = sb;
    for (int d = 1; d < 256; d <<= 1) {
        dst_[t] = (t >= d) ? (src_[t - d] + src_[t]) : src_[t];
        __syncthreads();
        int* tmp = src_; src_ = dst_; dst_ = tmp;
    }
    int inc  = src_[t];
    int excl = inc - s;
    int run = excl;
    for (int i = 0; i < chunk; i++) {
        int idx = base + i;
        if (idx < n) { off[idx] = run; run += deg[idx]; }
    }
    if (t == 255) off[n] = src_[255];
}

__global__ void fill_csr_kernel(const int* __restrict__ ei, int* __restrict__ cursor,
                                int* __restrict__ csr_src) {
    int e = blockIdx.x * blockDim.x + threadIdx.x;
    if (e >= N_TOT) return;
    int src, dst;
    if (e < N_EDGES) { src = ei[e]; dst = ei[N_EDGES + e]; }
    else             { src = dst = e - N_EDGES; }
    int pos = atomicAdd(&cursor[dst], 1);
    csr_src[pos] = src;
}

// ----------------------------- GEMM: h = x @ W ------------------------------
// block = 256 threads, 32 nodes per block. W is [Cin, Cout] row-major.
template<int Cin, int Cout>
__global__ void gemm_tile_kernel(const float* __restrict__ x, const float* __restrict__ W,
                                 float* __restrict__ h) {
    static_assert(256 % Cout == 0 || Cout % 256 == 0, "");
    __shared__ float xs[32][Cin];
    int n0 = blockIdx.x * 32;
    int tid = threadIdx.x;
    for (int i = tid; i < 32 * Cin; i += 256) {
        int n = i / Cin, k = i % Cin;
        int gn = n0 + n;
        xs[n][k] = (gn < N_NODES) ? x[(size_t)gn * Cin + k] : 0.f;
    }
    __syncthreads();
    constexpr int NS   = 256 / Cout;   // distinct node-subgroups per block
    constexpr int NACC = 32 / NS;      // nodes per thread
    int oc   = tid % Cout;
    int nsub = tid / Cout;
    float acc[NACC];
#pragma unroll
    for (int i = 0; i < NACC; i++) acc[i] = 0.f;
    for (int k = 0; k < Cin; k++) {
        float w = W[(size_t)k * Cout + oc];
#pragma unroll
        for (int i = 0; i < NACC; i++) acc[i] += xs[nsub + i * NS][k] * w;
    }
#pragma unroll
    for (int i = 0; i < NACC; i++) {
        int gn = n0 + nsub + i * NS;
        if (gn < N_NODES) h[(size_t)gn * Cout + oc] = acc[i];
    }
}

// ------------------- per-node attention logits al_s, al_d -------------------
template<int H, int C>
__global__ void attn_logits_kernel(const float* __restrict__ h, const float* __restrict__ a_src,
                                   const float* __restrict__ a_dst, float* __restrict__ al_s,
                                   float* __restrict__ al_d) {
    int i = blockIdx.x * blockDim.x + threadIdx.x;   // (n, head)
    if (i >= N_NODES * H) return;
    int n = i / H, head = i % H;
    const float4* hp = (const float4*)(h + (size_t)n * H * C + head * C);
    const float4* as4 = (const float4*)(a_src + head * C);
    const float4* ad4 = (const float4*)(a_dst + head * C);
    float ss = 0.f, sd = 0.f;
#pragma unroll
    for (int c = 0; c < C / 4; c++) {
        float4 v = hp[c], a = as4[c], d = ad4[c];
        ss += v.x * a.x + v.y * a.y + v.z * a.z + v.w * a.w;
        sd += v.x * d.x + v.y * d.y + v.z * d.z + v.w * d.w;
    }
    al_s[i] = ss;
    al_d[i] = sd;
}

// ------------------------- GAT softmax + aggregation ------------------------
// One group of G = H*C/4 lanes per node. Each lane owns 4 output channels
// (float4). Phase 1: per-lane online softmax over ALL H heads (m[H], s[H]
// in registers), al_s row loaded as float4s; shfl-xor butterfly merge.
// Phase 2: one float4 h-gather per lane per edge (whole row in G dwordx4).
template<int H, int C, bool RELU>
__global__ void gat_agg_kernel(const float* __restrict__ h, const float* __restrict__ al_s,
                               const float* __restrict__ al_d, const int* __restrict__ off,
                               const int* __restrict__ csr_src, const float* __restrict__ bias,
                               float* __restrict__ out) {
    constexpr int HC  = H * C;
    constexpr int G   = HC / 4;    // lanes per node (64 / 32 / 8)
    constexpr int NPW = 64 / G;    // nodes per wave
    constexpr int NPB = 4 * NPW;   // nodes per 256-thread block

    int tid  = threadIdx.x;
    int wid  = tid >> 6;
    int lane = tid & 63;
    int gi   = lane / G;           // node slot within wave
    int g    = lane % G;           // lane within node group
    int node = blockIdx.x * NPB + wid * NPW + gi;
    if (node >= N_NODES) return;

    int r0 = off[node], r1 = off[node + 1];
    int head = (4 * g) / C;

    float ald[H];
#pragma unroll
    for (int hh = 0; hh < H; hh++) ald[hh] = al_d[node * H + hh];

    // ---- phase 1: online softmax over incoming edges, all H heads/lane ----
    float m[H], s[H];
#pragma unroll
    for (int hh = 0; hh < H; hh++) { m[hh] = -INFINITY; s[hh] = 0.f; }

    for (int j = r0 + g; j < r1; j += G) {
        int src = csr_src[j];
        float als[H];
        if constexpr (H == 8) {
            float4 a0 = ((const float4*)al_s)[src * 2];
            float4 a1 = ((const float4*)al_s)[src * 2 + 1];
            als[0] = a0.x; als[1] = a0.y; als[2] = a0.z; als[3] = a0.w;
            als[4] = a1.x; als[5] = a1.y; als[6] = a1.z; als[7] = a1.w;
        } else {
            als[0] = al_s[src];
        }
#pragma unroll
        for (int hh = 0; hh < H; hh++) {
            float e = als[hh] + ald[hh];
            e = (e > 0.f) ? e : 0.2f * e;
            float M = fmaxf(m[hh], e);
            s[hh] = s[hh] * __expf(m[hh] - M) + __expf(e - M);
            m[hh] = M;
        }
    }
#pragma unroll
    for (int k = 1; k < G; k <<= 1) {
#pragma unroll
        for (int hh = 0; hh < H; hh++) {
            float om = __shfl_xor(m[hh], k, 64);
            float os = __shfl_xor(s[hh], k, 64);
            float M = fmaxf(m[hh], om);
            float S;
            if (M == -INFINITY) S = 0.f;   // guard NaN from (-inf) - (-inf)
            else S = s[hh] * __expf(m[hh] - M) + os * __expf(om - M);
            m[hh] = M; s[hh] = S;
        }
    }
    float mh    = m[head];
    float inv_s = 1.f / s[head];   // s >= 1: every node has a self loop
    float aldh  = ald[head];

    // ---- phase 2: weighted aggregation, float4 channels per lane ----
    float4 acc = make_float4(0.f, 0.f, 0.f, 0.f);
    for (int j = r0; j < r1; j++) {
        int src = csr_src[j];
        float e = al_s[src * H + head] + aldh;
        e = (e > 0.f) ? e : 0.2f * e;
        float w = __expf(e - mh) * inv_s;
        float4 hv = ((const float4*)(h + (size_t)src * HC))[g];
        acc.x += w * hv.x; acc.y += w * hv.y; acc.z += w * hv.z; acc.w += w * hv.w;
    }
    float4 bv = ((const float4*)bias)[g];
    acc.x += bv.x; acc.y += bv.y; acc.z += bv.z; acc.w += bv.w;
    if (RELU) {
        acc.x = fmaxf(acc.x, 0.f); acc.y = fmaxf(acc.y, 0.f);
        acc.z = fmaxf(acc.z, 0.f); acc.w = fmaxf(acc.w, 0.f);
    }
    ((float4*)(out + (size_t)node * HC))[g] = acc;
}

// ------------------------------- launcher -----------------------------------
extern "C" void kernel_launch(void* const* d_in, const int* in_sizes, int n_in,
                              void* d_out, int out_size, void* d_ws, size_t ws_size,
                              hipStream_t stream) {
    const float* x   = (const float*)d_in[0];
    const int*   ei  = (const int*)d_in[1];   // harness casts int64 -> int32
    const float* W1  = (const float*)d_in[2];
    const float* as1 = (const float*)d_in[3];
    const float* ad1 = (const float*)d_in[4];
    const float* b1  = (const float*)d_in[5];
    const float* W2  = (const float*)d_in[6];
    const float* as2 = (const float*)d_in[7];
    const float* ad2 = (const float*)d_in[8];
    const float* b2  = (const float*)d_in[9];
    const float* W3  = (const float*)d_in[10];
    const float* as3 = (const float*)d_in[11];
    const float* ad3 = (const float*)d_in[12];
    const float* b3  = (const float*)d_in[13];
    const float* W4  = (const float*)d_in[14];
    const float* as4 = (const float*)d_in[15];
    const float* ad4 = (const float*)d_in[16];
    const float* b4  = (const float*)d_in[17];

    char* ws = (char*)d_ws;
    size_t o = 0;
    auto alloc = [&](size_t bytes) -> void* {
        void* p = ws + o;
        o = (o + bytes + 255) & ~(size_t)255;
        return p;
    };
    float* feat_a  = (float*)alloc((size_t)N_NODES * 256 * 4);  // 51.2 MB
    float* feat_b  = (float*)alloc((size_t)N_NODES * 32 * 4);   // 6.4 MB
    float* h_buf   = (float*)alloc((size_t)N_NODES * 256 * 4);  // 51.2 MB
    float* al_s    = (float*)alloc((size_t)N_NODES * 8 * 4);
    float* al_d    = (float*)alloc((size_t)N_NODES * 8 * 4);
    int*   deg     = (int*)alloc((size_t)(N_NODES + 1) * 4);
    int*   off     = (int*)alloc((size_t)(N_NODES + 1) * 4);
    int*   cursor  = (int*)alloc((size_t)N_NODES * 4);
    int*   csr_src = (int*)alloc((size_t)N_TOT * 4);

    const int TPB = 256;
    int nb_nodes = (N_NODES + TPB - 1) / TPB;
    int nb_edges = (N_TOT + TPB - 1) / TPB;
    int nb_gemm  = (N_NODES + 31) / 32;

    // ---- CSR build (by dst) ----
    zero_int_kernel<<<nb_nodes, TPB, 0, stream>>>(deg, N_NODES);
    deg_hist_kernel<<<nb_edges, TPB, 0, stream>>>(ei, deg);
    scan_offsets_kernel<<<1, TPB, 0, stream>>>(deg, off);
    copy_int_kernel<<<nb_nodes, TPB, 0, stream>>>(off, cursor, N_NODES);
    fill_csr_kernel<<<nb_edges, TPB, 0, stream>>>(ei, cursor, csr_src);

    // nodes per block for gat_agg: NPB = 4 * 64 / (H*C/4)
    auto agg_blocks = [](int hc) { return (N_NODES * (hc / 4) + 255) / 256; };

    // ---- Layer 1: 128 -> (8 heads x 32), ReLU ----
    gemm_tile_kernel<128, 256><<<nb_gemm, TPB, 0, stream>>>(x, W1, h_buf);
    attn_logits_kernel<8, 32><<<(N_NODES * 8 + TPB - 1) / TPB, TPB, 0, stream>>>(h_buf, as1, ad1, al_s, al_d);
    gat_agg_kernel<8, 32, true><<<agg_blocks(256), TPB, 0, stream>>>(h_buf, al_s, al_d, off, csr_src, b1, feat_a);

    // ---- Layer 2: 256 -> 32, 1 head ----
    gemm_tile_kernel<256, 32><<<nb_gemm, TPB, 0, stream>>>(feat_a, W2, h_buf);
    attn_logits_kernel<1, 32><<<(N_NODES + TPB - 1) / TPB, TPB, 0, stream>>>(h_buf, as2, ad2, al_s, al_d);
    gat_agg_kernel<1, 32, false><<<agg_blocks(32), TPB, 0, stream>>>(h_buf, al_s, al_d, off, csr_src, b2, feat_b);

    // ---- Layer 3: 32 -> (8 heads x 32), ReLU ----
    gemm_tile_kernel<32, 256><<<nb_gemm, TPB, 0, stream>>>(feat_b, W3, h_buf);
    attn_logits_kernel<8, 32><<<(N_NODES * 8 + TPB - 1) / TPB, TPB, 0, stream>>>(h_buf, as3, ad3, al_s, al_d);
    gat_agg_kernel<8, 32, true><<<agg_blocks(256), TPB, 0, stream>>>(h_buf, al_s, al_d, off, csr_src, b3, feat_a);

    // ---- Layer 4: 256 -> 128, 1 head ----
    gemm_tile_kernel<256, 128><<<nb_gemm, TPB, 0, stream>>>(feat_a, W4, h_buf);
    attn_logits_kernel<1, 128><<<(N_NODES + TPB - 1) / TPB, TPB, 0, stream>>>(h_buf, as4, ad4, al_s, al_d);
    gat_agg_kernel<1, 128, false><<<agg_blocks(128), TPB, 0, stream>>>(h_buf, al_s, al_d, off, csr_src, b4, (float*)d_out);
}

// Round 4
// 978.350 us; speedup vs baseline: 1.5179x; 1.0466x over previous
//
#include <hip/hip_runtime.h>
#include <math.h>

#define N_NODES 50000
#define N_EDGES 800000
#define N_TOT   850000   // edges + self loops

// ----------------------------- utility kernels -----------------------------
__global__ void zero_int_kernel(int* p, int n) {
    int i = blockIdx.x * blockDim.x + threadIdx.x;
    if (i < n) p[i] = 0;
}

__global__ void copy_int_kernel(const int* a, int* b, int n) {
    int i = blockIdx.x * blockDim.x + threadIdx.x;
    if (i < n) b[i] = a[i];
}

// ----------------------------- CSR build -----------------------------------
// NOTE: harness delivers integer inputs as int32 (int64 in reference is cast).
__global__ void deg_hist_kernel(const int* __restrict__ ei, int* __restrict__ deg) {
    int e = blockIdx.x * blockDim.x + threadIdx.x;
    if (e >= N_TOT) return;
    int dst = (e < N_EDGES) ? ei[N_EDGES + e] : (e - N_EDGES);
    atomicAdd(&deg[dst], 1);
}

// single block, 256 threads: exclusive scan of deg[0..N_NODES) -> off[0..N_NODES]
__global__ void scan_offsets_kernel(const int* __restrict__ deg, int* __restrict__ off) {
    __shared__ int sa[256], sb[256];
    const int n = N_NODES;
    int t = threadIdx.x;
    const int chunk = (n + 255) / 256;
    int base = t * chunk;
    int s = 0;
    for (int i = 0; i < chunk; i++) {
        int idx = base + i;
        if (idx < n) s += deg[idx];
    }
    sa[t] = s;
    __syncthreads();
    int* src_ = sa; int* dst_ = sb;
    for (int d = 1; d < 256; d <<= 1) {
        dst_[t] = (t >= d) ? (src_[t - d] + src_[t]) : src_[t];
        __syncthreads();
        int* tmp = src_; src_ = dst_; dst_ = tmp;
    }
    int inc  = src_[t];
    int excl = inc - s;
    int run = excl;
    for (int i = 0; i < chunk; i++) {
        int idx = base + i;
        if (idx < n) { off[idx] = run; run += deg[idx]; }
    }
    if (t == 255) off[n] = src_[255];
}

__global__ void fill_csr_kernel(const int* __restrict__ ei, int* __restrict__ cursor,
                                int* __restrict__ csr_src) {
    int e = blockIdx.x * blockDim.x + threadIdx.x;
    if (e >= N_TOT) return;
    int src, dst;
    if (e < N_EDGES) { src = ei[e]; dst = ei[N_EDGES + e]; }
    else             { src = dst = e - N_EDGES; }
    int pos = atomicAdd(&cursor[dst], 1);
    csr_src[pos] = src;
}

// ----------------------------- GEMM: h = x @ W ------------------------------
// block = 256 threads, 32 nodes per block. W is [Cin, Cout] row-major.
template<int Cin, int Cout>
__global__ void gemm_tile_kernel(const float* __restrict__ x, const float* __restrict__ W,
                                 float* __restrict__ h) {
    static_assert(256 % Cout == 0 || Cout % 256 == 0, "");
    __shared__ float xs[32][Cin];
    int n0 = blockIdx.x * 32;
    int tid = threadIdx.x;
    for (int i = tid; i < 32 * Cin; i += 256) {
        int n = i / Cin, k = i % Cin;
        int gn = n0 + n;
        xs[n][k] = (gn < N_NODES) ? x[(size_t)gn * Cin + k] : 0.f;
    }
    __syncthreads();
    constexpr int NS   = 256 / Cout;   // distinct node-subgroups per block
    constexpr int NACC = 32 / NS;      // nodes per thread
    int oc   = tid % Cout;
    int nsub = tid / Cout;
    float acc[NACC];
#pragma unroll
    for (int i = 0; i < NACC; i++) acc[i] = 0.f;
    for (int k = 0; k < Cin; k++) {
        float w = W[(size_t)k * Cout + oc];
#pragma unroll
        for (int i = 0; i < NACC; i++) acc[i] += xs[nsub + i * NS][k] * w;
    }
#pragma unroll
    for (int i = 0; i < NACC; i++) {
        int gn = n0 + nsub + i * NS;
        if (gn < N_NODES) h[(size_t)gn * Cout + oc] = acc[i];
    }
}

// ------------------- per-node attention logits al_s, al_d -------------------
template<int H, int C>
__global__ void attn_logits_kernel(const float* __restrict__ h, const float* __restrict__ a_src,
                                   const float* __restrict__ a_dst, float* __restrict__ al_s,
                                   float* __restrict__ al_d) {
    int i = blockIdx.x * blockDim.x + threadIdx.x;   // (n, head)
    if (i >= N_NODES * H) return;
    int n = i / H, head = i % H;
    const float4* hp = (const float4*)(h + (size_t)n * H * C + head * C);
    const float4* as4 = (const float4*)(a_src + head * C);
    const float4* ad4 = (const float4*)(a_dst + head * C);
    float ss = 0.f, sd = 0.f;
#pragma unroll
    for (int c = 0; c < C / 4; c++) {
        float4 v = hp[c], a = as4[c], d = ad4[c];
        ss += v.x * a.x + v.y * a.y + v.z * a.z + v.w * a.w;
        sd += v.x * d.x + v.y * d.y + v.z * d.z + v.w * d.w;
    }
    al_s[i] = ss;
    al_d[i] = sd;
}

// ------------------------- GAT softmax + aggregation ------------------------
// One group of G = H*C/4 lanes per node; each lane owns 4 output channels
// (float4) of head = g/SUB where SUB = G/H lanes serve each head.
// Phase 1: lane handles ONLY its own head, edges strided by SUB; butterfly
//   over log2(SUB) stages puts (m,s) for head h exactly in head-h lanes.
// Phase 2: chunks of SUB edges; each lane computes ONE (edge,head) weight
//   (one exp covers the whole chunk), gather loop fetches w/src via shfl.
template<int H, int C, bool RELU>
__global__ void gat_agg_kernel(const float* __restrict__ h, const float* __restrict__ al_s,
                               const float* __restrict__ al_d, const int* __restrict__ off,
                               const int* __restrict__ csr_src, const float* __restrict__ bias,
                               float* __restrict__ out) {
    constexpr int HC  = H * C;
    constexpr int G   = HC / 4;    // lanes per node (64 / 32 / 8)
    constexpr int SUB = G / H;     // lanes per head = edge-parallel width
    constexpr int NPW = 64 / G;    // nodes per wave
    constexpr int NPB = 4 * NPW;   // nodes per 256-thread block

    int tid  = threadIdx.x;
    int wid  = tid >> 6;
    int lane = tid & 63;
    int gi   = lane / G;           // node slot within wave
    int g    = lane % G;           // lane within node group
    int node = blockIdx.x * NPB + wid * NPW + gi;
    if (node >= N_NODES) return;

    int head = g / SUB;            // this lane's head
    int es   = g % SUB;            // edge-stride slot within head group
    int r0 = off[node], r1 = off[node + 1];
    float ald = al_d[node * H + head];

    // ---- phase 1: online softmax for OWN head, edges strided by SUB ----
    float m = -INFINITY, s = 0.f;
    for (int j = r0 + es; j < r1; j += SUB) {
        int src = csr_src[j];
        float e = al_s[src * H + head] + ald;
        e = (e > 0.f) ? e : 0.2f * e;
        float M = fmaxf(m, e);
        s = s * __expf(m - M) + __expf(e - M);
        m = M;
    }
#pragma unroll
    for (int k = 1; k < SUB; k <<= 1) {
        float om = __shfl_xor(m, k, 64);
        float os = __shfl_xor(s, k, 64);
        float M = fmaxf(m, om);
        float S;
        if (M == -INFINITY) S = 0.f;   // guard NaN from (-inf) - (-inf)
        else S = s * __expf(m - M) + os * __expf(om - M);
        m = M; s = S;
    }
    float inv_s = 1.f / s;             // s >= 1: every node has a self loop

    // ---- phase 2: chunks of SUB edges; one weight per lane per chunk ----
    int gwave = gi * G;                // wave-lane base of this node's group
    float4 acc = make_float4(0.f, 0.f, 0.f, 0.f);
    for (int j0 = r0; j0 < r1; j0 += SUB) {
        int je = j0 + es;
        bool valid = je < r1;
        int src_e = csr_src[valid ? je : (r1 - 1)];
        float e = al_s[src_e * H + head] + ald;
        e = (e > 0.f) ? e : 0.2f * e;
        float w = valid ? __expf(e - m) * inv_s : 0.f;
        int cnt = (r1 - j0 < SUB) ? (r1 - j0) : SUB;
        for (int e2 = 0; e2 < cnt; e2++) {
            float we   = __shfl(w, gwave + head * SUB + e2, 64);
            int   srce = __shfl(src_e, gwave + e2, 64);
            float4 hv = ((const float4*)(h + (size_t)srce * HC))[g];
            acc.x += we * hv.x; acc.y += we * hv.y;
            acc.z += we * hv.z; acc.w += we * hv.w;
        }
    }
    float4 bv = ((const float4*)bias)[g];
    acc.x += bv.x; acc.y += bv.y; acc.z += bv.z; acc.w += bv.w;
    if (RELU) {
        acc.x = fmaxf(acc.x, 0.f); acc.y = fmaxf(acc.y, 0.f);
        acc.z = fmaxf(acc.z, 0.f); acc.w = fmaxf(acc.w, 0.f);
    }
    ((float4*)(out + (size_t)node * HC))[g] = acc;
}

// ------------------------------- launcher -----------------------------------
extern "C" void kernel_launch(void* const* d_in, const int* in_sizes, int n_in,
                              void* d_out, int out_size, void* d_ws, size_t ws_size,
                              hipStream_t stream) {
    const float* x   = (const float*)d_in[0];
    const int*   ei  = (const int*)d_in[1];   // harness casts int64 -> int32
    const float* W1  = (const float*)d_in[2];
    const float* as1 = (const float*)d_in[3];
    const float* ad1 = (const float*)d_in[4];
    const float* b1  = (const float*)d_in[5];
    const float* W2  = (const float*)d_in[6];
    const float* as2 = (const float*)d_in[7];
    const float* ad2 = (const float*)d_in[8];
    const float* b2  = (const float*)d_in[9];
    const float* W3  = (const float*)d_in[10];
    const float* as3 = (const float*)d_in[11];
    const float* ad3 = (const float*)d_in[12];
    const float* b3  = (const float*)d_in[13];
    const float* W4  = (const float*)d_in[14];
    const float* as4 = (const float*)d_in[15];
    const float* ad4 = (const float*)d_in[16];
    const float* b4  = (const float*)d_in[17];

    char* ws = (char*)d_ws;
    size_t o = 0;
    auto alloc = [&](size_t bytes) -> void* {
        void* p = ws + o;
        o = (o + bytes + 255) & ~(size_t)255;
        return p;
    };
    float* feat_a  = (float*)alloc((size_t)N_NODES * 256 * 4);  // 51.2 MB
    float* feat_b  = (float*)alloc((size_t)N_NODES * 32 * 4);   // 6.4 MB
    float* h_buf   = (float*)alloc((size_t)N_NODES * 256 * 4);  // 51.2 MB
    float* al_s    = (float*)alloc((size_t)N_NODES * 8 * 4);
    float* al_d    = (float*)alloc((size_t)N_NODES * 8 * 4);
    int*   deg     = (int*)alloc((size_t)(N_NODES + 1) * 4);
    int*   off     = (int*)alloc((size_t)(N_NODES + 1) * 4);
    int*   cursor  = (int*)alloc((size_t)N_NODES * 4);
    int*   csr_src = (int*)alloc((size_t)N_TOT * 4);

    const int TPB = 256;
    int nb_nodes = (N_NODES + TPB - 1) / TPB;
    int nb_edges = (N_TOT + TPB - 1) / TPB;
    int nb_gemm  = (N_NODES + 31) / 32;

    // ---- CSR build (by dst) ----
    zero_int_kernel<<<nb_nodes, TPB, 0, stream>>>(deg, N_NODES);
    deg_hist_kernel<<<nb_edges, TPB, 0, stream>>>(ei, deg);
    scan_offsets_kernel<<<1, TPB, 0, stream>>>(deg, off);
    copy_int_kernel<<<nb_nodes, TPB, 0, stream>>>(off, cursor, N_NODES);
    fill_csr_kernel<<<nb_edges, TPB, 0, stream>>>(ei, cursor, csr_src);

    // nodes per block for gat_agg: NPB = 4 * 64 / (H*C/4)
    auto agg_blocks = [](int hc) { return (N_NODES * (hc / 4) + 255) / 256; };

    // ---- Layer 1: 128 -> (8 heads x 32), ReLU ----
    gemm_tile_kernel<128, 256><<<nb_gemm, TPB, 0, stream>>>(x, W1, h_buf);
    attn_logits_kernel<8, 32><<<(N_NODES * 8 + TPB - 1) / TPB, TPB, 0, stream>>>(h_buf, as1, ad1, al_s, al_d);
    gat_agg_kernel<8, 32, true><<<agg_blocks(256), TPB, 0, stream>>>(h_buf, al_s, al_d, off, csr_src, b1, feat_a);

    // ---- Layer 2: 256 -> 32, 1 head ----
    gemm_tile_kernel<256, 32><<<nb_gemm, TPB, 0, stream>>>(feat_a, W2, h_buf);
    attn_logits_kernel<1, 32><<<(N_NODES + TPB - 1) / TPB, TPB, 0, stream>>>(h_buf, as2, ad2, al_s, al_d);
    gat_agg_kernel<1, 32, false><<<agg_blocks(32), TPB, 0, stream>>>(h_buf, al_s, al_d, off, csr_src, b2, feat_b);

    // ---- Layer 3: 32 -> (8 heads x 32), ReLU ----
    gemm_tile_kernel<32, 256><<<nb_gemm, TPB, 0, stream>>>(feat_b, W3, h_buf);
    attn_logits_kernel<8, 32><<<(N_NODES * 8 + TPB - 1) / TPB, TPB, 0, stream>>>(h_buf, as3, ad3, al_s, al_d);
    gat_agg_kernel<8, 32, true><<<agg_blocks(256), TPB, 0, stream>>>(h_buf, al_s, al_d, off, csr_src, b3, feat_a);

    // ---- Layer 4: 256 -> 128, 1 head ----
    gemm_tile_kernel<256, 128><<<nb_gemm, TPB, 0, stream>>>(feat_a, W4, h_buf);
    attn_logits_kernel<1, 128><<<(N_NODES + TPB - 1) / TPB, TPB, 0, stream>>>(h_buf, as4, ad4, al_s, al_d);
    gat_agg_kernel<1, 128, false><<<agg_blocks(128), TPB, 0, stream>>>(h_buf, al_s, al_d, off, csr_src, b4, (float*)d_out);
}

// Round 5
// 890.261 us; speedup vs baseline: 1.6681x; 1.0989x over previous
//
#include <hip/hip_runtime.h>
#include <math.h>

#define N_NODES 50000
#define N_EDGES 800000
#define N_TOT   850000   // edges + self loops

// ----------------------------- utility kernels -----------------------------
__global__ void zero_int_kernel(int* p, int n) {
    int i = blockIdx.x * blockDim.x + threadIdx.x;
    if (i < n) p[i] = 0;
}

__global__ void copy_int_kernel(const int* a, int* b, int n) {
    int i = blockIdx.x * blockDim.x + threadIdx.x;
    if (i < n) b[i] = a[i];
}

// ----------------------------- CSR build -----------------------------------
// NOTE: harness delivers integer inputs as int32 (int64 in reference is cast).
__global__ void deg_hist_kernel(const int* __restrict__ ei, int* __restrict__ deg) {
    int e = blockIdx.x * blockDim.x + threadIdx.x;
    if (e >= N_TOT) return;
    int dst = (e < N_EDGES) ? ei[N_EDGES + e] : (e - N_EDGES);
    atomicAdd(&deg[dst], 1);
}

// single block, 256 threads: exclusive scan of deg[0..N_NODES) -> off[0..N_NODES]
__global__ void scan_offsets_kernel(const int* __restrict__ deg, int* __restrict__ off) {
    __shared__ int sa[256], sb[256];
    const int n = N_NODES;
    int t = threadIdx.x;
    const int chunk = (n + 255) / 256;
    int base = t * chunk;
    int s = 0;
    for (int i = 0; i < chunk; i++) {
        int idx = base + i;
        if (idx < n) s += deg[idx];
    }
    sa[t] = s;
    __syncthreads();
    int* src_ = sa; int* dst_ = sb;
    for (int d = 1; d < 256; d <<= 1) {
        dst_[t] = (t >= d) ? (src_[t - d] + src_[t]) : src_[t];
        __syncthreads();
        int* tmp = src_; src_ = dst_; dst_ = tmp;
    }
    int inc  = src_[t];
    int excl = inc - s;
    int run = excl;
    for (int i = 0; i < chunk; i++) {
        int idx = base + i;
        if (idx < n) { off[idx] = run; run += deg[idx]; }
    }
    if (t == 255) off[n] = src_[255];
}

__global__ void fill_csr_kernel(const int* __restrict__ ei, int* __restrict__ cursor,
                                int* __restrict__ csr_src) {
    int e = blockIdx.x * blockDim.x + threadIdx.x;
    if (e >= N_TOT) return;
    int src, dst;
    if (e < N_EDGES) { src = ei[e]; dst = ei[N_EDGES + e]; }
    else             { src = dst = e - N_EDGES; }
    int pos = atomicAdd(&cursor[dst], 1);
    csr_src[pos] = src;
}

// ----------------------------- GEMM: h = x @ W ------------------------------
// block = 256 threads, 32 nodes per block. W is [Cin, Cout] row-major.
// Register tiling: each thread owns OCP=4 output channels x NACC nodes.
// Per k: NACC LDS broadcasts + OCP cached W loads + OCP*NACC FMAs (ratio 4:1).
template<int Cin, int Cout>
__global__ void gemm_tile_kernel(const float* __restrict__ x, const float* __restrict__ W,
                                 float* __restrict__ h) {
    constexpr int OCP  = 4;
    constexpr int OCT  = Cout / OCP;     // oc-threads: 64 / 32 / 8
    constexpr int NG   = 256 / OCT;      // node groups: 4 / 8 / 32
    constexpr int NACC = 32 / NG;        // nodes per thread: 8 / 4 / 1
    __shared__ float xs[32][Cin];
    int n0  = blockIdx.x * 32;
    int tid = threadIdx.x;
    // coalesced float4 staging of 32 node rows
    for (int i = tid; i < 32 * Cin / 4; i += 256) {
        int n = i / (Cin / 4), k4 = i % (Cin / 4);
        int gn = n0 + n;
        float4 v = (gn < N_NODES) ? ((const float4*)(x + (size_t)gn * Cin))[k4]
                                  : make_float4(0.f, 0.f, 0.f, 0.f);
        ((float4*)xs[n])[k4] = v;
    }
    __syncthreads();
    int oct  = tid % OCT;
    int nsub = tid / OCT;
    float acc[NACC][OCP];
#pragma unroll
    for (int i = 0; i < NACC; i++)
#pragma unroll
        for (int j = 0; j < OCP; j++) acc[i][j] = 0.f;

#pragma unroll 4
    for (int k = 0; k < Cin; k++) {
        float wv[OCP];
#pragma unroll
        for (int j = 0; j < OCP; j++) wv[j] = W[(size_t)k * Cout + oct + j * OCT];
#pragma unroll
        for (int i = 0; i < NACC; i++) {
            float xv = xs[nsub * NACC + i][k];
#pragma unroll
            for (int j = 0; j < OCP; j++) acc[i][j] += xv * wv[j];
        }
    }
#pragma unroll
    for (int i = 0; i < NACC; i++) {
        int gn = n0 + nsub * NACC + i;
        if (gn < N_NODES) {
#pragma unroll
            for (int j = 0; j < OCP; j++)
                h[(size_t)gn * Cout + oct + j * OCT] = acc[i][j];
        }
    }
}

// ------------------- per-node attention logits al_s, al_d -------------------
template<int H, int C>
__global__ void attn_logits_kernel(const float* __restrict__ h, const float* __restrict__ a_src,
                                   const float* __restrict__ a_dst, float* __restrict__ al_s,
                                   float* __restrict__ al_d) {
    int i = blockIdx.x * blockDim.x + threadIdx.x;   // (n, head)
    if (i >= N_NODES * H) return;
    int n = i / H, head = i % H;
    const float4* hp = (const float4*)(h + (size_t)n * H * C + head * C);
    const float4* as4 = (const float4*)(a_src + head * C);
    const float4* ad4 = (const float4*)(a_dst + head * C);
    float ss = 0.f, sd = 0.f;
#pragma unroll
    for (int c = 0; c < C / 4; c++) {
        float4 v = hp[c], a = as4[c], d = ad4[c];
        ss += v.x * a.x + v.y * a.y + v.z * a.z + v.w * a.w;
        sd += v.x * d.x + v.y * d.y + v.z * d.z + v.w * d.w;
    }
    al_s[i] = ss;
    al_d[i] = sd;
}

// ------------------------- GAT softmax + aggregation ------------------------
// One group of G = H*C/4 lanes per node; each lane owns 4 output channels
// (float4) of head = g/SUB where SUB = G/H lanes serve each head.
// Phase 1: lane handles ONLY its own head, edges strided by SUB; butterfly
//   over log2(SUB) stages puts (m,s) for head h exactly in head-h lanes.
// Phase 2: chunks of SUB edges; each lane computes ONE (edge,head) weight.
//   Full chunks take a compile-time unrolled path (SUB gathers in flight).
template<int H, int C, bool RELU>
__global__ void gat_agg_kernel(const float* __restrict__ h, const float* __restrict__ al_s,
                               const float* __restrict__ al_d, const int* __restrict__ off,
                               const int* __restrict__ csr_src, const float* __restrict__ bias,
                               float* __restrict__ out) {
    constexpr int HC  = H * C;
    constexpr int G   = HC / 4;    // lanes per node (64 / 32 / 8)
    constexpr int SUB = G / H;     // lanes per head = edge-parallel width
    constexpr int NPW = 64 / G;    // nodes per wave
    constexpr int NPB = 4 * NPW;   // nodes per 256-thread block

    int tid  = threadIdx.x;
    int wid  = tid >> 6;
    int lane = tid & 63;
    int gi   = lane / G;           // node slot within wave
    int g    = lane % G;           // lane within node group
    int node = blockIdx.x * NPB + wid * NPW + gi;
    if (node >= N_NODES) return;

    int head = g / SUB;            // this lane's head
    int es   = g % SUB;            // edge-stride slot within head group
    int r0 = off[node], r1 = off[node + 1];
    float ald = al_d[node * H + head];

    // ---- phase 1: online softmax for OWN head, edges strided by SUB ----
    float m = -INFINITY, s = 0.f;
    for (int j = r0 + es; j < r1; j += SUB) {
        int src = csr_src[j];
        float e = al_s[src * H + head] + ald;
        e = (e > 0.f) ? e : 0.2f * e;
        float M = fmaxf(m, e);
        s = s * __expf(m - M) + __expf(e - M);
        m = M;
    }
#pragma unroll
    for (int k = 1; k < SUB; k <<= 1) {
        float om = __shfl_xor(m, k, 64);
        float os = __shfl_xor(s, k, 64);
        float M = fmaxf(m, om);
        float S;
        if (M == -INFINITY) S = 0.f;   // guard NaN from (-inf) - (-inf)
        else S = s * __expf(m - M) + os * __expf(om - M);
        m = M; s = S;
    }
    float inv_s = 1.f / s;             // s >= 1: every node has a self loop

    // ---- phase 2: chunks of SUB edges; one weight per lane per chunk ----
    int gwave = gi * G;                // wave-lane base of this node's group
    const float4* hv4 = (const float4*)h;
    float4 acc = make_float4(0.f, 0.f, 0.f, 0.f);
    for (int j0 = r0; j0 < r1; j0 += SUB) {
        int je = j0 + es;
        bool valid = je < r1;
        int src_e = csr_src[valid ? je : (r1 - 1)];
        float e = al_s[src_e * H + head] + ald;
        e = (e > 0.f) ? e : 0.2f * e;
        float w = valid ? __expf(e - m) * inv_s : 0.f;
        if (j0 + SUB <= r1) {
            // full chunk: fixed trip count -> all SUB gathers in flight
#pragma unroll
            for (int e2 = 0; e2 < SUB; e2++) {
                float we   = __shfl(w, gwave + head * SUB + e2, 64);
                int   srce = __shfl(src_e, gwave + e2, 64);
                float4 hv = hv4[(size_t)srce * (HC / 4) + g];
                acc.x += we * hv.x; acc.y += we * hv.y;
                acc.z += we * hv.z; acc.w += we * hv.w;
            }
        } else {
            int cnt = r1 - j0;
#pragma unroll 4
            for (int e2 = 0; e2 < cnt; e2++) {
                float we   = __shfl(w, gwave + head * SUB + e2, 64);
                int   srce = __shfl(src_e, gwave + e2, 64);
                float4 hv = hv4[(size_t)srce * (HC / 4) + g];
                acc.x += we * hv.x; acc.y += we * hv.y;
                acc.z += we * hv.z; acc.w += we * hv.w;
            }
        }
    }
    float4 bv = ((const float4*)bias)[g];
    acc.x += bv.x; acc.y += bv.y; acc.z += bv.z; acc.w += bv.w;
    if (RELU) {
        acc.x = fmaxf(acc.x, 0.f); acc.y = fmaxf(acc.y, 0.f);
        acc.z = fmaxf(acc.z, 0.f); acc.w = fmaxf(acc.w, 0.f);
    }
    ((float4*)(out + (size_t)node * HC))[g] = acc;
}

// ------------------------------- launcher -----------------------------------
extern "C" void kernel_launch(void* const* d_in, const int* in_sizes, int n_in,
                              void* d_out, int out_size, void* d_ws, size_t ws_size,
                              hipStream_t stream) {
    const float* x   = (const float*)d_in[0];
    const int*   ei  = (const int*)d_in[1];   // harness casts int64 -> int32
    const float* W1  = (const float*)d_in[2];
    const float* as1 = (const float*)d_in[3];
    const float* ad1 = (const float*)d_in[4];
    const float* b1  = (const float*)d_in[5];
    const float* W2  = (const float*)d_in[6];
    const float* as2 = (const float*)d_in[7];
    const float* ad2 = (const float*)d_in[8];
    const float* b2  = (const float*)d_in[9];
    const float* W3  = (const float*)d_in[10];
    const float* as3 = (const float*)d_in[11];
    const float* ad3 = (const float*)d_in[12];
    const float* b3  = (const float*)d_in[13];
    const float* W4  = (const float*)d_in[14];
    const float* as4 = (const float*)d_in[15];
    const float* ad4 = (const float*)d_in[16];
    const float* b4  = (const float*)d_in[17];

    char* ws = (char*)d_ws;
    size_t o = 0;
    auto alloc = [&](size_t bytes) -> void* {
        void* p = ws + o;
        o = (o + bytes + 255) & ~(size_t)255;
        return p;
    };
    float* feat_a  = (float*)alloc((size_t)N_NODES * 256 * 4);  // 51.2 MB
    float* feat_b  = (float*)alloc((size_t)N_NODES * 32 * 4);   // 6.4 MB
    float* h_buf   = (float*)alloc((size_t)N_NODES * 256 * 4);  // 51.2 MB
    float* al_s    = (float*)alloc((size_t)N_NODES * 8 * 4);
    float* al_d    = (float*)alloc((size_t)N_NODES * 8 * 4);
    int*   deg     = (int*)alloc((size_t)(N_NODES + 1) * 4);
    int*   off     = (int*)alloc((size_t)(N_NODES + 1) * 4);
    int*   cursor  = (int*)alloc((size_t)N_NODES * 4);
    int*   csr_src = (int*)alloc((size_t)N_TOT * 4);

    const int TPB = 256;
    int nb_nodes = (N_NODES + TPB - 1) / TPB;
    int nb_edges = (N_TOT + TPB - 1) / TPB;
    int nb_gemm  = (N_NODES + 31) / 32;

    // ---- CSR build (by dst) ----
    zero_int_kernel<<<nb_nodes, TPB, 0, stream>>>(deg, N_NODES);
    deg_hist_kernel<<<nb_edges, TPB, 0, stream>>>(ei, deg);
    scan_offsets_kernel<<<1, TPB, 0, stream>>>(deg, off);
    copy_int_kernel<<<nb_nodes, TPB, 0, stream>>>(off, cursor, N_NODES);
    fill_csr_kernel<<<nb_edges, TPB, 0, stream>>>(ei, cursor, csr_src);

    // nodes per block for gat_agg: NPB = 4 * 64 / (H*C/4)
    auto agg_blocks = [](int hc) { return (N_NODES * (hc / 4) + 255) / 256; };

    // ---- Layer 1: 128 -> (8 heads x 32), ReLU ----
    gemm_tile_kernel<128, 256><<<nb_gemm, TPB, 0, stream>>>(x, W1, h_buf);
    attn_logits_kernel<8, 32><<<(N_NODES * 8 + TPB - 1) / TPB, TPB, 0, stream>>>(h_buf, as1, ad1, al_s, al_d);
    gat_agg_kernel<8, 32, true><<<agg_blocks(256), TPB, 0, stream>>>(h_buf, al_s, al_d, off, csr_src, b1, feat_a);

    // ---- Layer 2: 256 -> 32, 1 head ----
    gemm_tile_kernel<256, 32><<<nb_gemm, TPB, 0, stream>>>(feat_a, W2, h_buf);
    attn_logits_kernel<1, 32><<<(N_NODES + TPB - 1) / TPB, TPB, 0, stream>>>(h_buf, as2, ad2, al_s, al_d);
    gat_agg_kernel<1, 32, false><<<agg_blocks(32), TPB, 0, stream>>>(h_buf, al_s, al_d, off, csr_src, b2, feat_b);

    // ---- Layer 3: 32 -> (8 heads x 32), ReLU ----
    gemm_tile_kernel<32, 256><<<nb_gemm, TPB, 0, stream>>>(feat_b, W3, h_buf);
    attn_logits_kernel<8, 32><<<(N_NODES * 8 + TPB - 1) / TPB, TPB, 0, stream>>>(h_buf, as3, ad3, al_s, al_d);
    gat_agg_kernel<8, 32, true><<<agg_blocks(256), TPB, 0, stream>>>(h_buf, al_s, al_d, off, csr_src, b3, feat_a);

    // ---- Layer 4: 256 -> 128, 1 head ----
    gemm_tile_kernel<256, 128><<<nb_gemm, TPB, 0, stream>>>(feat_a, W4, h_buf);
    attn_logits_kernel<1, 128><<<(N_NODES + TPB - 1) / TPB, TPB, 0, stream>>>(h_buf, as4, ad4, al_s, al_d);
    gat_agg_kernel<1, 128, false><<<agg_blocks(128), TPB, 0, stream>>>(h_buf, al_s, al_d, off, csr_src, b4, (float*)d_out);
}